// Round 6
// baseline (37.305 us; speedup 1.0000x reference)
//
#include <hip/hip_runtime.h>

// REINFORCE fused kernel — fully wave-independent version.
// B=1024 rows, T=8192. Each WAVE owns a 1024-elem chunk (16/lane); incoming
// carry computed in-wave from a 1024-elem halo (gamma^1024=3.35e-5).
// No __syncthreads, no LDS: every wave runs load->scan->epilogue unblocked.
// XCD swizzle: all 8 chunks of a row share bid%8 -> same XCD L2 (halo = L2 hit).

#define T_LEN 8192
#define NT 256
#define GAMMA_F 0.99f
#define CLIP_F 5.0f
#define EPS_F 1e-7f
#define L2G 0.0144995696951151f   // -log2(0.99)

typedef float f32x4 __attribute__((ext_vector_type(4)));

constexpr double dgpow(int n) {
    double r = 1.0;
    for (int i = 0; i < n; ++i) r *= 0.99;
    return r;
}

__device__ __forceinline__ float r2f(float w, float x) {
    float s = 1.0f / (1.0f + __expf(-x));
    return w * w * __logf(s + EPS_F);
}

__global__ __launch_bounds__(NT)
void reinforce_kernel(const float* __restrict__ log_probs,
                      const float* __restrict__ logits,
                      const float* __restrict__ weight,
                      float* __restrict__ out,   // [2*B*T]: objective, then cumulative
                      long BT) {
    // Block covers 4096 elems (4 waves x 1024). 2 blocks per row.
    // Swizzle: both blocks of a row share bid%8 -> same XCD.
    const int bid  = blockIdx.x;            // 0..2047
    const int k    = bid & 7;
    const int j    = bid >> 3;              // 0..255
    const int half = j & 1;
    const int row  = (j >> 1) * 8 + k;      // 0..1023

    const int wave = threadIdx.x >> 6;
    const int lane = threadIdx.x & 63;
    const int gc   = half * 4 + wave;       // global chunk 0..7 within row

    const long rbase = (long)row * T_LEN;
    const long lbase = rbase + (long)gc * 1024 + lane * 16;   // this lane's 16 elems

    const f32x4* w4 = reinterpret_cast<const f32x4*>(weight + lbase);
    const f32x4* x4 = reinterpret_cast<const f32x4*>(logits + lbase);
    const f32x4* l4 = reinterpret_cast<const f32x4*>(log_probs + lbase);

    const bool has_halo = (gc != 7);

    // ---- issue all loads (chunk w/x/lp + halo w/x); compiler interleaves waits
    f32x4 wq[4], xq[4], lq[4], hw[4], hx[4];
#pragma unroll
    for (int q = 0; q < 4; ++q) { wq[q] = w4[q]; xq[q] = x4[q]; }
    if (has_halo) {
        const f32x4* hw4 = reinterpret_cast<const f32x4*>(weight + lbase + 1024);
        const f32x4* hx4 = reinterpret_cast<const f32x4*>(logits + lbase + 1024);
#pragma unroll
        for (int q = 0; q < 4; ++q) { hw[q] = hw4[q]; hx[q] = hx4[q]; }
    }
#pragma unroll
    for (int q = 0; q < 4; ++q) lq[q] = l4[q];

    // ---- chunk r2
    float r2[16];
#pragma unroll
    for (int q = 0; q < 4; ++q)
#pragma unroll
        for (int e = 0; e < 4; ++e)
            r2[4 * q + e] = r2f(wq[q][e], xq[q][e]);

    // ---- per-lane suffix sum over own 16 elems (zero carry)
    float S = 0.0f;
#pragma unroll
    for (int jj = 15; jj >= 0; --jj) S = r2[jj] + GAMMA_F * S;

    // ---- in-wave suffix scan (decay gamma^16 per lane step)
    float X = S;
    {
        constexpr float G16  = (float)dgpow(16);
        constexpr float G32  = (float)dgpow(32);
        constexpr float G64  = (float)dgpow(64);
        constexpr float G128 = (float)dgpow(128);
        constexpr float G256 = (float)dgpow(256);
        constexpr float G512 = (float)dgpow(512);
        float t;
        t = __shfl_down(X, 1, 64);  if (lane + 1  < 64) X += G16  * t;
        t = __shfl_down(X, 2, 64);  if (lane + 2  < 64) X += G32  * t;
        t = __shfl_down(X, 4, 64);  if (lane + 4  < 64) X += G64  * t;
        t = __shfl_down(X, 8, 64);  if (lane + 8  < 64) X += G128 * t;
        t = __shfl_down(X, 16, 64); if (lane + 16 < 64) X += G256 * t;
        t = __shfl_down(X, 32, 64); if (lane + 32 < 64) X += G512 * t;
    }
    float Ex = __shfl_down(X, 1, 64);
    if (lane == 63) Ex = 0.0f;

    // ---- in-wave halo carry: c_in = sum_{k=0..1023} gamma^k r2[chunk_end + k]
    float c_in = 0.0f;
    if (has_halo) {
        float h2[16];
#pragma unroll
        for (int q = 0; q < 4; ++q)
#pragma unroll
            for (int e = 0; e < 4; ++e)
                h2[4 * q + e] = r2f(hw[q][e], hx[q][e]);
        float hS = 0.0f;
#pragma unroll
        for (int jj = 15; jj >= 0; --jj) hS = h2[jj] + GAMMA_F * hS;
        float part = exp2f((float)(lane << 4) * -L2G) * hS;
#pragma unroll
        for (int off = 1; off < 64; off <<= 1)
            part += __shfl_xor(part, off, 64);
        c_in = part;
    }

    // carry entering this lane's segment fixup (c at element (lane+1)*16)
    float K = Ex + exp2f((float)((63 - lane) << 4) * -L2G) * c_in;

    // ---- fixup scan + fused epilogue + stores
    f32x4* go = reinterpret_cast<f32x4*>(out + lbase);
    f32x4* co = reinterpret_cast<f32x4*>(out + BT + lbase);

    float c = K;
#pragma unroll
    for (int q = 3; q >= 0; --q) {
        f32x4 cq, gq;
#pragma unroll
        for (int e = 3; e >= 0; --e) {
            c = r2[4 * q + e] + GAMMA_F * c;
            cq[e] = c;
            float adv = fminf(fmaxf(wq[q][e] * c, -CLIP_F), CLIP_F);
            gq[e] = adv * lq[q][e];
        }
        co[q] = cq;
        go[q] = gq;
    }
}

extern "C" void kernel_launch(void* const* d_in, const int* in_sizes, int n_in,
                              void* d_out, int out_size, void* d_ws, size_t ws_size,
                              hipStream_t stream) {
    const float* log_probs = (const float*)d_in[0];
    const float* logits    = (const float*)d_in[1];
    const float* weight    = (const float*)d_in[2];
    // d_in[3] = baselines: unused by the reference computation.
    long BT = (long)in_sizes[0];
    int nblocks = (int)(BT / 4096);
    reinforce_kernel<<<nblocks, NT, 0, stream>>>(log_probs, logits, weight, (float*)d_out, BT);
}

// Round 7
// 31.039 us; speedup vs baseline: 1.2019x; 1.2019x over previous
//
#include <hip/hip_runtime.h>

// REINFORCE fused kernel, chunked with truncated-horizon halo.
// B=1024 rows, T=8192. Each row split into 8 chunks of 1024; each block (256 thr)
// owns one chunk (4 elems/thread); incoming carry from a 1024-elem halo
// (gamma^1024=3.35e-5). Round-7: CHUNK 2048->1024 => 8192 blocks = 4x wave-slot
// oversubscription (round 6 showed occupancy/backfill is the lever, not barriers).
// XCD swizzle: all 8 chunks of a row share bid%8 -> same XCD L2 (halo = L2 hit).

#define T_LEN 8192
#define CHUNK 1024
#define NT 256
#define CSEG 4
#define GAMMA_F 0.99f
#define CLIP_F 5.0f
#define EPS_F 1e-7f

typedef float f32x4 __attribute__((ext_vector_type(4)));

constexpr double dgpow(int n) {
    double r = 1.0;
    for (int i = 0; i < n; ++i) r *= 0.99;
    return r;
}

__device__ __forceinline__ float r2f(float w, float x) {
    float s = 1.0f / (1.0f + __expf(-x));
    return w * w * __logf(s + EPS_F);
}

__global__ __launch_bounds__(NT)
void reinforce_kernel(const float* __restrict__ log_probs,
                      const float* __restrict__ logits,
                      const float* __restrict__ weight,
                      float* __restrict__ out,   // [2*B*T]: objective, then cumulative
                      long BT) {
    // XCD-aware decode: all 8 chunks of a row share bid%8 -> same XCD L2,
    // and are adjacent in dispatch order (co-scheduled).
    const int bid   = blockIdx.x;          // 0..8191
    const int k     = bid & 7;             // xcd slot
    const int j     = bid >> 3;            // 0..1023
    const int chunk = j & 7;               // 0..7
    const int row   = (j >> 3) * 8 + k;    // 0..1023

    const long rbase = (long)row * T_LEN;
    const long cbase = rbase + (long)chunk * CHUNK;
    const int tid  = threadIdx.x;
    const int lane = tid & 63;
    const int wave = tid >> 6;
    const int seg  = tid * CSEG;

    __shared__ float RED[4];
    __shared__ float WT[4];

    const bool has_halo = (chunk != 7);

    // ---- issue ALL global loads up front (3 chunk + 2 halo f32x4 in flight) ----
    f32x4 hw, hx;
    if (has_halo) {
        const long hbase = cbase + CHUNK + (long)tid * 4;
        hw = *reinterpret_cast<const f32x4*>(weight + hbase);
        hx = *reinterpret_cast<const f32x4*>(logits + hbase);
    }
    f32x4 wq = *reinterpret_cast<const f32x4*>(weight + cbase + seg);
    f32x4 xq = *reinterpret_cast<const f32x4*>(logits + cbase + seg);
    f32x4 lq = *reinterpret_cast<const f32x4*>(log_probs + cbase + seg);

    // ---- chunk r2 ----
    float r2[CSEG];
#pragma unroll
    for (int e = 0; e < 4; ++e) r2[e] = r2f(wq[e], xq[e]);

    // ---- per-thread suffix sum (zero carry) ----
    float S = r2[3];
    S = r2[2] + GAMMA_F * S;
    S = r2[1] + GAMMA_F * S;
    S = r2[0] + GAMMA_F * S;

    // ---- wave suffix scan (decay gamma^4 per lane step) ----
    float X = S;
    {
        constexpr float G4   = (float)dgpow(4);
        constexpr float G8   = (float)dgpow(8);
        constexpr float G16  = (float)dgpow(16);
        constexpr float G32  = (float)dgpow(32);
        constexpr float G64  = (float)dgpow(64);
        constexpr float G128 = (float)dgpow(128);
        float t;
        t = __shfl_down(X, 1, 64);  if (lane + 1  < 64) X += G4   * t;
        t = __shfl_down(X, 2, 64);  if (lane + 2  < 64) X += G8   * t;
        t = __shfl_down(X, 4, 64);  if (lane + 4  < 64) X += G16  * t;
        t = __shfl_down(X, 8, 64);  if (lane + 8  < 64) X += G32  * t;
        t = __shfl_down(X, 16, 64); if (lane + 16 < 64) X += G64  * t;
        t = __shfl_down(X, 32, 64); if (lane + 32 < 64) X += G128 * t;
    }
    float Ex = __shfl_down(X, 1, 64);
    if (lane == 63) Ex = 0.0f;

    // ---- halo partial (independent of scan) ----
    if (has_halo) {
        float h0 = r2f(hw[0], hx[0]), h1 = r2f(hw[1], hx[1]);
        float h2 = r2f(hw[2], hx[2]), h3 = r2f(hw[3], hx[3]);
        float hS = h0 + GAMMA_F * (h1 + GAMMA_F * (h2 + GAMMA_F * h3));
        const float L2G4 = 4.0f * -0.014499569695f;   // 4*log2(0.99)
        float part = exp2f((float)tid * L2G4) * hS;
#pragma unroll
        for (int off = 1; off < 64; off <<= 1)
            part += __shfl_xor(part, off, 64);
        if (lane == 0) RED[wave] = part;
    }
    if (lane == 0) WT[wave] = X;

    __syncthreads();   // single barrier

    float c_in = has_halo ? (RED[0] + RED[1] + RED[2] + RED[3]) : 0.0f;

    // wave spans 256 elems
    constexpr float G256 = (float)dgpow(256);
    constexpr float G512 = (float)dgpow(512);
    constexpr float G768 = (float)dgpow(768);
    float WC;
    if (wave == 3)      WC = c_in;
    else if (wave == 2) WC = WT[3] + G256 * c_in;
    else if (wave == 1) WC = WT[2] + G256 * WT[3] + G512 * c_in;
    else                WC = WT[1] + G256 * WT[2] + G512 * WT[3] + G768 * c_in;

    const float L2G4 = 4.0f * -0.014499569695f;   // 4*log2(0.99)
    float K = Ex + exp2f((float)(63 - lane) * L2G4) * WC;

    // ---- fixup scan + fused epilogue + write-back stores ----
    f32x4 cq, gq;
    float c = K;
#pragma unroll
    for (int e = 3; e >= 0; --e) {
        c = r2[e] + GAMMA_F * c;
        cq[e] = c;
        float adv = fminf(fmaxf(wq[e] * c, -CLIP_F), CLIP_F);
        gq[e] = adv * lq[e];
    }
    *reinterpret_cast<f32x4*>(out + BT + cbase + seg) = cq;
    *reinterpret_cast<f32x4*>(out + cbase + seg)      = gq;
}

extern "C" void kernel_launch(void* const* d_in, const int* in_sizes, int n_in,
                              void* d_out, int out_size, void* d_ws, size_t ws_size,
                              hipStream_t stream) {
    const float* log_probs = (const float*)d_in[0];
    const float* logits    = (const float*)d_in[1];
    const float* weight    = (const float*)d_in[2];
    // d_in[3] = baselines: unused by the reference computation.
    long BT = (long)in_sizes[0];
    int nblocks = (int)(BT / CHUNK);
    reinforce_kernel<<<nblocks, NT, 0, stream>>>(log_probs, logits, weight, (float*)d_out, BT);
}